// Round 22
// baseline (101.756 us; speedup 1.0000x reference)
//
#include <hip/hip_runtime.h>

// ---------------------------------------------------------------------------
// Fused MLP-embedding cosine-similarity kernel for MI355X (gfx950).
//   e = (x @ W1^T + b1 -> selu) @ W2^T + b2 -> selu) @ W3^T + b3
//   out = sigmoid((cos(e1,e2)+1)/2)
// Round 22: identical to round 21 (infra failure — resubmitting).
// Delete the X-staging phase. P1 reads X fragments DIRECTLY from global
// (fp32 -> bf16 cvt in regs; rows are 128B-contiguous per fragment;
// L2-warm after first touch). This removes one phase + one barrier + the
// 16KB Xs buffer + 16 LDS reads/wave. h2 lives fully in P2's acc[4][4],
// retires h1 with one barrier, then writes into hA wholesale. LDS 48->34KB
// -> 4 blocks/CU capacity (launch_bounds(256,4), VGPR cap 128; r20's
// identical P2 compiles to 84). Register epilogue kept (r20 best, 57.7us).
// ---------------------------------------------------------------------------

typedef __bf16 bf16x8 __attribute__((ext_vector_type(8)));
typedef __bf16 bf16x4 __attribute__((ext_vector_type(4)));
typedef float  f32x4  __attribute__((ext_vector_type(4)));

constexpr int WS_W1 = 0;       // 16 tiles * 4 ks * 512 bf16
constexpr int WS_W2 = 32768;   // 16 tiles * 8 ks * 512
constexpr int WS_W3 = 98304;   //  8 tiles * 8 ks * 512

__device__ __forceinline__ float selu_f(float x) {
    const float scale = 1.0507009873554805f;
    const float sa    = 1.7580993408473766f;   // scale * alpha
    float xp = fmaxf(x, 0.f);
    float xn = fminf(x, 0.f);
    return fmaf(scale, xp, sa * (__expf(xn) - 1.f));
}

// activation fragment from LDS (stride 256 bf16, XOR-swizzled)
__device__ __forceinline__ bf16x8 read_act(const __bf16* lds, int row, int kcol) {
    unsigned byte = (unsigned)((row * 256 + kcol) * 2) ^ ((unsigned)(row & 7) << 4);
    return *(const bf16x8*)((const char*)lds + byte);
}

// store one D fragment: 4 consecutive neurons (col0..col0+3) at sample row
template<bool SELU>
__device__ __forceinline__ void store_act(__bf16* lds, int row, int col0, f32x4 a) {
    float v0 = a[0], v1 = a[1], v2 = a[2], v3 = a[3];
    if (SELU) { v0 = selu_f(v0); v1 = selu_f(v1); v2 = selu_f(v2); v3 = selu_f(v3); }
    bf16x4 u;
    u[0] = (__bf16)v0; u[1] = (__bf16)v1; u[2] = (__bf16)v2; u[3] = (__bf16)v3;
    unsigned byte = (unsigned)((row * 256 + col0) * 2) ^ ((unsigned)(row & 7) << 4);
    *(bf16x4*)((char*)lds + byte) = u;
}

// --- pre-kernel: fp32 weights -> bf16 A-fragment order ----------------------
// lane l of frag (t,ks) holds W[t*16 + (l&15)][ks*32 + (l>>4)*8 + j], j=0..7
__global__ void pack_weights_kernel(const float* __restrict__ W1,
                                    const float* __restrict__ W2,
                                    const float* __restrict__ W3,
                                    __bf16* __restrict__ ws) {
    int t = blockIdx.x * blockDim.x + threadIdx.x;      // 0..16383
    const float* W; int K, KS, f, base;
    if (t < 4096)       { W = W1; K = 128; KS = 4; f = t;         base = WS_W1; }
    else if (t < 12288) { W = W2; K = 256; KS = 8; f = t - 4096;  base = WS_W2; }
    else                { W = W3; K = 256; KS = 8; f = t - 12288; base = WS_W3; }
    int lane = f & 63;
    int ks   = (f >> 6) % KS;
    int ct   = f / (64 * KS);
    int row  = ct * 16 + (lane & 15);
    int k0   = ks * 32 + (lane >> 4) * 8;
    const float* src = W + (size_t)row * K + k0;
    __bf16* dst = ws + base + (size_t)f * 8;
#pragma unroll
    for (int j = 0; j < 8; ++j) dst[j] = (__bf16)src[j];
}

// --- main fused kernel ------------------------------------------------------
// 4 waves x 64 rows; wave owns 64 output cols (4 ntiles) in 256-col layers,
// 32 cols (2 ntiles) in the 128-col layer. No X staging: P1 reads global.
__global__ __launch_bounds__(256, 4)
void embed_sim_kernel(const float* __restrict__ s1, const float* __restrict__ s2,
                      const float* __restrict__ b1, const float* __restrict__ b2,
                      const float* __restrict__ b3,
                      const __bf16* __restrict__ wf, float* __restrict__ out) {
    __shared__ __align__(16) __bf16 hA[64 * 256];   // h1, then h2   (32 KB)
    __shared__ __align__(16) float  red[4 * 32 * 3]; // epilogue partials (1.5 KB)

    const int tid  = threadIdx.x;
    const int wave = tid >> 6;        // 0..3
    const int lane = tid & 63;
    const int lr   = lane & 15;
    const int kg   = lane >> 4;
    const int p0   = blockIdx.x * 32;

    // ---- P1: L1 (256 out; wave owns ntiles 4w..4w+3), X direct from global ----
    {
        bf16x8 wfr[4][4]; f32x4 bv[4];
#pragma unroll
        for (int ti = 0; ti < 4; ++ti) {
            int t = wave * 4 + ti;
#pragma unroll
            for (int ks = 0; ks < 4; ++ks)
                wfr[ti][ks] = *(const bf16x8*)(wf + WS_W1 + (size_t)((t * 4 + ks) * 64 + lane) * 8);
            bv[ti] = *(const f32x4*)(b1 + t * 16 + kg * 4);
        }
#pragma unroll
        for (int s = 0; s < 4; ++s) {
            const int row = s * 16 + lr;
            const float* xr = (row < 32) ? (s1 + (size_t)(p0 + row) * 128)
                                         : (s2 + (size_t)(p0 + row - 32) * 128);
            bf16x8 xfr[4];
#pragma unroll
            for (int ks = 0; ks < 4; ++ks) {
                const float* p = xr + ks * 32 + kg * 8;
                float4 v0 = *(const float4*)(p);
                float4 v1 = *(const float4*)(p + 4);
                bf16x8 w;
                w[0] = (__bf16)v0.x; w[1] = (__bf16)v0.y; w[2] = (__bf16)v0.z; w[3] = (__bf16)v0.w;
                w[4] = (__bf16)v1.x; w[5] = (__bf16)v1.y; w[6] = (__bf16)v1.z; w[7] = (__bf16)v1.w;
                xfr[ks] = w;
            }
#pragma unroll
            for (int ti = 0; ti < 4; ++ti) {
                f32x4 acc = bv[ti];
#pragma unroll
                for (int ks = 0; ks < 4; ++ks)
                    acc = __builtin_amdgcn_mfma_f32_16x16x32_bf16(wfr[ti][ks], xfr[ks], acc, 0, 0, 0);
                store_act<true>(hA, row, (wave * 4 + ti) * 16 + kg * 4, acc);
            }
        }
    }
    __syncthreads();

    // ---- P2: L2 full-K in regs (wave owns ntiles 4w..4w+3, all 4 stripes) ----
    {
        f32x4 acc[4][4];                  // [ti][stripe] = 64 VGPR
#pragma unroll
        for (int ti = 0; ti < 4; ++ti) {
            f32x4 b = *(const f32x4*)(b2 + (wave * 4 + ti) * 16 + kg * 4);
#pragma unroll
            for (int s = 0; s < 4; ++s) acc[ti][s] = b;
        }
#pragma unroll
        for (int kh = 0; kh < 2; ++kh) {  // two K-halves; weights 64 VGPR each
            bf16x8 wfr[4][4];
#pragma unroll
            for (int ti = 0; ti < 4; ++ti) {
                int t = wave * 4 + ti;
#pragma unroll
                for (int ks = 0; ks < 4; ++ks)
                    wfr[ti][ks] = *(const bf16x8*)(wf + WS_W2 + (size_t)((t * 8 + kh * 4 + ks) * 64 + lane) * 8);
            }
#pragma unroll
            for (int s = 0; s < 4; ++s) {
                const int row = s * 16 + lr;
                bf16x8 hfr[4];
#pragma unroll
                for (int ks = 0; ks < 4; ++ks)
                    hfr[ks] = read_act(hA, row, kh * 128 + ks * 32 + kg * 8);
#pragma unroll
                for (int ti = 0; ti < 4; ++ti)
#pragma unroll
                    for (int ks = 0; ks < 4; ++ks)
                        acc[ti][s] = __builtin_amdgcn_mfma_f32_16x16x32_bf16(
                            wfr[ti][ks], hfr[ks], acc[ti][s], 0, 0, 0);
            }
        }
        __syncthreads();                  // all h1 reads complete; hA dead
        // write h2 (selu) into hA wholesale — wave owns cols 64w..64w+63
#pragma unroll
        for (int ti = 0; ti < 4; ++ti)
#pragma unroll
            for (int s = 0; s < 4; ++s)
                store_act<true>(hA, s * 16 + lr, (wave * 4 + ti) * 16 + kg * 4, acc[ti][s]);
    }
    __syncthreads();

    // ---- P3: L3 (128 out; wave owns ntiles 2w,2w+1): hA (h2), acc in regs ----
    f32x4 acc3[2][4];                     // [ti][stripe]; stripes 0,1 = e1; 2,3 = e2
    {
#pragma unroll
        for (int ti = 0; ti < 2; ++ti) {
            f32x4 b = *(const f32x4*)(b3 + (wave * 2 + ti) * 16 + kg * 4);
#pragma unroll
            for (int s = 0; s < 4; ++s) acc3[ti][s] = b;
        }
#pragma unroll
        for (int kh = 0; kh < 2; ++kh) {
            bf16x8 wfr[2][4];
#pragma unroll
            for (int ti = 0; ti < 2; ++ti) {
                int t = wave * 2 + ti;
#pragma unroll
                for (int ks = 0; ks < 4; ++ks)
                    wfr[ti][ks] = *(const bf16x8*)(wf + WS_W3 + (size_t)((t * 8 + kh * 4 + ks) * 64 + lane) * 8);
            }
#pragma unroll
            for (int s = 0; s < 4; ++s) {
                const int row = s * 16 + lr;
                bf16x8 hfr[4];
#pragma unroll
                for (int ks = 0; ks < 4; ++ks)
                    hfr[ks] = read_act(hA, row, kh * 128 + ks * 32 + kg * 8);
#pragma unroll
                for (int ti = 0; ti < 2; ++ti)
#pragma unroll
                    for (int ks = 0; ks < 4; ++ks)
                        acc3[ti][s] = __builtin_amdgcn_mfma_f32_16x16x32_bf16(
                            wfr[ti][ks], hfr[ks], acc3[ti][s], 0, 0, 0);
            }
        }
    }

    // ---- register epilogue: e1 = stripes 0,1; e2 = stripes 2,3 (same thread) ----
    {
        float d0 = 0.f, a0 = 0.f, c0 = 0.f;   // pair lr
        float d1 = 0.f, a1 = 0.f, c1 = 0.f;   // pair 16+lr
#pragma unroll
        for (int ti = 0; ti < 2; ++ti)
#pragma unroll
            for (int j = 0; j < 4; ++j) {
                float e1a = acc3[ti][0][j], e2a = acc3[ti][2][j];
                float e1b = acc3[ti][1][j], e2b = acc3[ti][3][j];
                d0 = fmaf(e1a, e2a, d0); a0 = fmaf(e1a, e1a, a0); c0 = fmaf(e2a, e2a, c0);
                d1 = fmaf(e1b, e2b, d1); a1 = fmaf(e1b, e1b, a1); c1 = fmaf(e2b, e2b, c1);
            }
#pragma unroll
        for (int off = 16; off < 64; off <<= 1) {   // reduce over kg groups
            d0 += __shfl_xor(d0, off); a0 += __shfl_xor(a0, off); c0 += __shfl_xor(c0, off);
            d1 += __shfl_xor(d1, off); a1 += __shfl_xor(a1, off); c1 += __shfl_xor(c1, off);
        }
        if (kg == 0) {                               // one rep per pair per wave
            float* r0 = red + ((wave * 32) + lr) * 3;
            r0[0] = d0; r0[1] = a0; r0[2] = c0;
            float* r1 = red + ((wave * 32) + 16 + lr) * 3;
            r1[0] = d1; r1[1] = a1; r1[2] = c1;
        }
    }
    __syncthreads();

    if (tid < 32) {
        const int p = tid;
        float D = 0.f, A = 0.f, C = 0.f;
#pragma unroll
        for (int w = 0; w < 4; ++w) {
            const float* r = red + ((w * 32) + p) * 3;
            D += r[0]; A += r[1]; C += r[2];
        }
        float r = D * rsqrtf(A * C);
        float x = (r + 1.f) * 0.5f;
        out[p0 + p] = 1.f / (1.f + __expf(-x));
    }
}

// ---------------------------------------------------------------------------
extern "C" void kernel_launch(void* const* d_in, const int* in_sizes, int n_in,
                              void* d_out, int out_size, void* d_ws, size_t ws_size,
                              hipStream_t stream) {
    const float* s1 = (const float*)d_in[0];
    const float* s2 = (const float*)d_in[1];
    const float* W1 = (const float*)d_in[2];
    const float* b1 = (const float*)d_in[3];
    const float* W2 = (const float*)d_in[4];
    const float* b2 = (const float*)d_in[5];
    const float* W3 = (const float*)d_in[6];
    const float* b3 = (const float*)d_in[7];
    __bf16* wf = (__bf16*)d_ws;                 // 256 KiB of d_ws
    float*  outp = (float*)d_out;

    pack_weights_kernel<<<64, 256, 0, stream>>>(W1, W2, W3, wf);

    const int npairs = in_sizes[0] / 128;       // 65536
    embed_sim_kernel<<<npairs / 32, 256, 0, stream>>>(s1, s2, b1, b2, b3, wf, outp);
}

// Round 23
// 57.633 us; speedup vs baseline: 1.7656x; 1.7656x over previous
//
#include <hip/hip_runtime.h>

// ---------------------------------------------------------------------------
// Fused MLP-embedding cosine-similarity kernel for MI355X (gfx950).
//   e = (x @ W1^T + b1 -> selu) @ W2^T + b2 -> selu) @ W3^T + b3
//   out = sigmoid((cos(e1,e2)+1)/2)
// Round 23: REVERT to round 20 (session best, 57.7us) after r22's
// X-direct-read experiment hit the register-allocator spill regime
// (VGPR 64, 186MB spill writes, 101.8us). r20 = r14 structure (4 waves x
// 64 rows, XOR-swizzled LDS, full-col wave partition, K-half weight
// streaming) + register epilogue. All isolated levers exhausted
// (r7,r11,r13-r22); this is the 3-phase structure's practical floor.
// ---------------------------------------------------------------------------

typedef __bf16 bf16x8 __attribute__((ext_vector_type(8)));
typedef __bf16 bf16x4 __attribute__((ext_vector_type(4)));
typedef float  f32x4  __attribute__((ext_vector_type(4)));

constexpr int WS_W1 = 0;       // 16 tiles * 4 ks * 512 bf16
constexpr int WS_W2 = 32768;   // 16 tiles * 8 ks * 512
constexpr int WS_W3 = 98304;   //  8 tiles * 8 ks * 512

__device__ __forceinline__ float selu_f(float x) {
    const float scale = 1.0507009873554805f;
    const float sa    = 1.7580993408473766f;   // scale * alpha
    float xp = fmaxf(x, 0.f);
    float xn = fminf(x, 0.f);
    return fmaf(scale, xp, sa * (__expf(xn) - 1.f));
}

// activation fragment (B-operand): lane holds X[row][kcol .. kcol+7]
template<int COLS>
__device__ __forceinline__ bf16x8 read_act(const __bf16* lds, int row, int kcol) {
    unsigned byte = (unsigned)((row * COLS + kcol) * 2) ^ ((unsigned)(row & 7) << 4);
    return *(const bf16x8*)((const char*)lds + byte);
}

// store one D fragment: 4 consecutive neurons (col0..col0+3) at sample row
template<bool SELU, int COLS>
__device__ __forceinline__ void store_act(__bf16* lds, int row, int col0, f32x4 a) {
    float v0 = a[0], v1 = a[1], v2 = a[2], v3 = a[3];
    if (SELU) { v0 = selu_f(v0); v1 = selu_f(v1); v2 = selu_f(v2); v3 = selu_f(v3); }
    bf16x4 u;
    u[0] = (__bf16)v0; u[1] = (__bf16)v1; u[2] = (__bf16)v2; u[3] = (__bf16)v3;
    unsigned byte = (unsigned)((row * COLS + col0) * 2) ^ ((unsigned)(row & 7) << 4);
    *(bf16x4*)((char*)lds + byte) = u;
}

// --- pre-kernel: fp32 weights -> bf16 A-fragment order ----------------------
// lane l of frag (t,ks) holds W[t*16 + (l&15)][ks*32 + (l>>4)*8 + j], j=0..7
__global__ void pack_weights_kernel(const float* __restrict__ W1,
                                    const float* __restrict__ W2,
                                    const float* __restrict__ W3,
                                    __bf16* __restrict__ ws) {
    int t = blockIdx.x * blockDim.x + threadIdx.x;      // 0..16383
    const float* W; int K, KS, f, base;
    if (t < 4096)       { W = W1; K = 128; KS = 4; f = t;         base = WS_W1; }
    else if (t < 12288) { W = W2; K = 256; KS = 8; f = t - 4096;  base = WS_W2; }
    else                { W = W3; K = 256; KS = 8; f = t - 12288; base = WS_W3; }
    int lane = f & 63;
    int ks   = (f >> 6) % KS;
    int ct   = f / (64 * KS);
    int row  = ct * 16 + (lane & 15);
    int k0   = ks * 32 + (lane >> 4) * 8;
    const float* src = W + (size_t)row * K + k0;
    __bf16* dst = ws + base + (size_t)f * 8;
#pragma unroll
    for (int j = 0; j < 8; ++j) dst[j] = (__bf16)src[j];
}

// --- main fused kernel ------------------------------------------------------
// 4 waves x 64 rows; wave owns 64 output cols (4 ntiles) in 256-col layers,
// 32 cols (2 ntiles) in the 128-col layer.
__global__ __launch_bounds__(256, 3)
void embed_sim_kernel(const float* __restrict__ s1, const float* __restrict__ s2,
                      const float* __restrict__ b1, const float* __restrict__ b2,
                      const float* __restrict__ b3,
                      const __bf16* __restrict__ wf, float* __restrict__ out) {
    __shared__ __align__(16) __bf16 Xs[64 * 128];   // X, later h2[:,0:128]
    __shared__ __align__(16) __bf16 hA[64 * 256];   // h1; later h2-hi (front) + red (back)

    const int tid  = threadIdx.x;
    const int wave = tid >> 6;        // 0..3
    const int lane = tid & 63;
    const int lr   = lane & 15;
    const int kg   = lane >> 4;
    const int p0   = blockIdx.x * 32;

    __bf16* h2hi = hA;                          // [64][128] after h1 dead
    float*  red  = (float*)(hA + 64 * 128);     // [4][32][3] partials (h1-hi dead in P3)

    // ---- stage X: rows 0..31 = s1, rows 32..63 = s2 ----
#pragma unroll
    for (int it = 0; it < 4; ++it) {
        int idx = tid + it * 256;            // 0..1023
        int row = idx >> 4;
        int k0  = (idx & 15) << 3;
        const float* src = (row < 32) ? (s1 + (size_t)(p0 + row) * 128 + k0)
                                      : (s2 + (size_t)(p0 + row - 32) * 128 + k0);
        float4 v0 = *(const float4*)(src);
        float4 v1 = *(const float4*)(src + 4);
        bf16x8 w;
        w[0] = (__bf16)v0.x; w[1] = (__bf16)v0.y; w[2] = (__bf16)v0.z; w[3] = (__bf16)v0.w;
        w[4] = (__bf16)v1.x; w[5] = (__bf16)v1.y; w[6] = (__bf16)v1.z; w[7] = (__bf16)v1.w;
        unsigned byte = (unsigned)((row * 128 + k0) * 2) ^ ((unsigned)(row & 7) << 4);
        *(bf16x8*)((char*)Xs + byte) = w;
    }
    __syncthreads();

    // ---- P1: L1 (256 out; wave owns ntiles 4w..4w+3) Xs -> hA[64][256] ----
    {
        bf16x8 wfr[4][4]; f32x4 bv[4];
#pragma unroll
        for (int ti = 0; ti < 4; ++ti) {
            int t = wave * 4 + ti;
#pragma unroll
            for (int ks = 0; ks < 4; ++ks)
                wfr[ti][ks] = *(const bf16x8*)(wf + WS_W1 + (size_t)((t * 4 + ks) * 64 + lane) * 8);
            bv[ti] = *(const f32x4*)(b1 + t * 16 + kg * 4);
        }
#pragma unroll
        for (int s = 0; s < 4; ++s) {
            const int row = s * 16 + lr;
            bf16x8 xfr[4];
#pragma unroll
            for (int ks = 0; ks < 4; ++ks) xfr[ks] = read_act<128>(Xs, row, ks * 32 + kg * 8);
#pragma unroll
            for (int ti = 0; ti < 4; ++ti) {
                f32x4 acc = bv[ti];
#pragma unroll
                for (int ks = 0; ks < 4; ++ks)
                    acc = __builtin_amdgcn_mfma_f32_16x16x32_bf16(wfr[ti][ks], xfr[ks], acc, 0, 0, 0);
                store_act<true, 256>(hA, row, (wave * 4 + ti) * 16 + kg * 4, acc);
            }
        }
    }
    __syncthreads();

    // ---- P2: L2 full-K in regs (wave owns ntiles 4w..4w+3, all 4 stripes) ----
    {
        f32x4 acc[4][4];                  // [ti][stripe] = 64 VGPR
#pragma unroll
        for (int ti = 0; ti < 4; ++ti) {
            f32x4 b = *(const f32x4*)(b2 + (wave * 4 + ti) * 16 + kg * 4);
#pragma unroll
            for (int s = 0; s < 4; ++s) acc[ti][s] = b;
        }
#pragma unroll
        for (int kh = 0; kh < 2; ++kh) {  // two K-halves; weights 64 VGPR each
            bf16x8 wfr[4][4];
#pragma unroll
            for (int ti = 0; ti < 4; ++ti) {
                int t = wave * 4 + ti;
#pragma unroll
                for (int ks = 0; ks < 4; ++ks)
                    wfr[ti][ks] = *(const bf16x8*)(wf + WS_W2 + (size_t)((t * 8 + kh * 4 + ks) * 64 + lane) * 8);
            }
#pragma unroll
            for (int s = 0; s < 4; ++s) {
                const int row = s * 16 + lr;
                bf16x8 hfr[4];
#pragma unroll
                for (int ks = 0; ks < 4; ++ks)
                    hfr[ks] = read_act<256>(hA, row, kh * 128 + ks * 32 + kg * 8);
#pragma unroll
                for (int ti = 0; ti < 4; ++ti)
#pragma unroll
                    for (int ks = 0; ks < 4; ++ks)
                        acc[ti][s] = __builtin_amdgcn_mfma_f32_16x16x32_bf16(
                            wfr[ti][ks], hfr[ks], acc[ti][s], 0, 0, 0);
            }
        }
        // h2-lo (waves 0,1 -> cols 0..127) over dead X — safe pre-barrier
        if (wave < 2) {
#pragma unroll
            for (int ti = 0; ti < 4; ++ti)
#pragma unroll
                for (int s = 0; s < 4; ++s)
                    store_act<true, 128>(Xs, s * 16 + lr, (wave * 4 + ti) * 16 + kg * 4, acc[ti][s]);
        }
        __syncthreads();                  // all hA (h1) reads complete
        // h2-hi (waves 2,3 -> cols 128..255) over hA front — h1 dead now
        if (wave >= 2) {
#pragma unroll
            for (int ti = 0; ti < 4; ++ti)
#pragma unroll
                for (int s = 0; s < 4; ++s)
                    store_act<true, 128>(h2hi, s * 16 + lr, ((wave - 2) * 4 + ti) * 16 + kg * 4, acc[ti][s]);
        }
    }
    __syncthreads();

    // ---- P3: L3 (128 out; wave owns ntiles 2w,2w+1): Xs + h2hi, acc in regs ----
    f32x4 acc3[2][4];                     // [ti][stripe]; stripes 0,1 = e1; 2,3 = e2
    {
#pragma unroll
        for (int ti = 0; ti < 2; ++ti) {
            f32x4 b = *(const f32x4*)(b3 + (wave * 2 + ti) * 16 + kg * 4);
#pragma unroll
            for (int s = 0; s < 4; ++s) acc3[ti][s] = b;
        }
#pragma unroll
        for (int kh = 0; kh < 2; ++kh) {
            const __bf16* src = (kh == 0) ? Xs : h2hi;
            bf16x8 wfr[2][4];
#pragma unroll
            for (int ti = 0; ti < 2; ++ti) {
                int t = wave * 2 + ti;
#pragma unroll
                for (int ks = 0; ks < 4; ++ks)
                    wfr[ti][ks] = *(const bf16x8*)(wf + WS_W3 + (size_t)((t * 8 + kh * 4 + ks) * 64 + lane) * 8);
            }
#pragma unroll
            for (int s = 0; s < 4; ++s) {
                const int row = s * 16 + lr;
                bf16x8 hfr[4];
#pragma unroll
                for (int ks = 0; ks < 4; ++ks)
                    hfr[ks] = read_act<128>(src, row, ks * 32 + kg * 8);
#pragma unroll
                for (int ti = 0; ti < 2; ++ti)
#pragma unroll
                    for (int ks = 0; ks < 4; ++ks)
                        acc3[ti][s] = __builtin_amdgcn_mfma_f32_16x16x32_bf16(
                            wfr[ti][ks], hfr[ks], acc3[ti][s], 0, 0, 0);
            }
        }
    }

    // ---- register epilogue: e1 = stripes 0,1; e2 = stripes 2,3 (same thread) ----
    // pair p = lr (s=0 vs 2) and p = 16+lr (s=1 vs 3); this wave's 32 neurons
    // split across kg-groups; reduce over kg via shfl_xor(16,32).
    {
        float d0 = 0.f, a0 = 0.f, c0 = 0.f;   // pair lr
        float d1 = 0.f, a1 = 0.f, c1 = 0.f;   // pair 16+lr
#pragma unroll
        for (int ti = 0; ti < 2; ++ti)
#pragma unroll
            for (int j = 0; j < 4; ++j) {
                float e1a = acc3[ti][0][j], e2a = acc3[ti][2][j];
                float e1b = acc3[ti][1][j], e2b = acc3[ti][3][j];
                d0 = fmaf(e1a, e2a, d0); a0 = fmaf(e1a, e1a, a0); c0 = fmaf(e2a, e2a, c0);
                d1 = fmaf(e1b, e2b, d1); a1 = fmaf(e1b, e1b, a1); c1 = fmaf(e2b, e2b, c1);
            }
#pragma unroll
        for (int off = 16; off < 64; off <<= 1) {   // reduce over kg groups
            d0 += __shfl_xor(d0, off); a0 += __shfl_xor(a0, off); c0 += __shfl_xor(c0, off);
            d1 += __shfl_xor(d1, off); a1 += __shfl_xor(a1, off); c1 += __shfl_xor(c1, off);
        }
        if (kg == 0) {                               // one rep per pair per wave
            float* r0 = red + ((wave * 32) + lr) * 3;
            r0[0] = d0; r0[1] = a0; r0[2] = c0;
            float* r1 = red + ((wave * 32) + 16 + lr) * 3;
            r1[0] = d1; r1[1] = a1; r1[2] = c1;
        }
    }
    __syncthreads();

    if (tid < 32) {
        const int p = tid;
        float D = 0.f, A = 0.f, C = 0.f;
#pragma unroll
        for (int w = 0; w < 4; ++w) {
            const float* r = red + ((w * 32) + p) * 3;
            D += r[0]; A += r[1]; C += r[2];
        }
        float r = D * rsqrtf(A * C);
        float x = (r + 1.f) * 0.5f;
        out[p0 + p] = 1.f / (1.f + __expf(-x));
    }
}

// ---------------------------------------------------------------------------
extern "C" void kernel_launch(void* const* d_in, const int* in_sizes, int n_in,
                              void* d_out, int out_size, void* d_ws, size_t ws_size,
                              hipStream_t stream) {
    const float* s1 = (const float*)d_in[0];
    const float* s2 = (const float*)d_in[1];
    const float* W1 = (const float*)d_in[2];
    const float* b1 = (const float*)d_in[3];
    const float* W2 = (const float*)d_in[4];
    const float* b2 = (const float*)d_in[5];
    const float* W3 = (const float*)d_in[6];
    const float* b3 = (const float*)d_in[7];
    __bf16* wf = (__bf16*)d_ws;                 // 256 KiB of d_ws
    float*  outp = (float*)d_out;

    pack_weights_kernel<<<64, 256, 0, stream>>>(W1, W2, W3, wf);

    const int npairs = in_sizes[0] / 128;       // 65536
    embed_sim_kernel<<<npairs / 32, 256, 0, stream>>>(s1, s2, b1, b2, b3, wf, outp);
}